// Round 2
// baseline (2571.634 us; speedup 1.0000x reference)
//
#include <hip/hip_runtime.h>
#include <math.h>

#define NGRAPH 1024
#define NN     256      // nodes per graph (layer-1)
#define NE     2048     // edges per graph
#define EMB    39       // input feature dim
#define HD     64       // hidden dim
#define STRIDE 65       // node-major LDS row stride (pad +1: all patterns <=2-way bank aliased = free)
#define NT     1024     // threads per block (16 waves -> 4 waves/SIMD at 1 block/CU)
#define TRASH  255      // scatter sink row for invalid edges (never a live node in layers 2/3)

// k1=ceil(0.8*256)=205, k2=164, k3=132 (double semantics verified; R0 passed absmax=0)
#define K1 205
#define K2 164
#define K3 132

#define BUF_F (NN * STRIDE)   // 16640 floats per ping-pong buffer

// LDS budget (bytes):
//  bufA+bufB 2*66560=133120 ; erec 2048*8=16384 (redmax/redsum aliased inside)
//  deg/score/sctmp/rnkcnt 4*1024=4096 ; feats 512 ; pn 256 ; mlp1 256 ; mlp2 128
//  epack0 4096 ; nodemap 512  -> total 159360 < 163840 -> 1 block/CU, 16 waves
#define SMEM_BYTES 159360

__global__ __launch_bounds__(NT, 4) void gnn_pool_kernel(
    const float* __restrict__ gx, const int* __restrict__ gedge,
    const float* __restrict__ W1, const float* __restrict__ b1, const float* __restrict__ p1,
    const float* __restrict__ W2, const float* __restrict__ b2, const float* __restrict__ p2,
    const float* __restrict__ W3, const float* __restrict__ b3, const float* __restrict__ p3,
    const float* __restrict__ lW1, const float* __restrict__ lb1,
    const float* __restrict__ lW2, const float* __restrict__ lb2,
    const float* __restrict__ lW3, const float* __restrict__ lb3,
    float* __restrict__ gout)
{
    extern __shared__ __align__(16) char smem_raw[];
    float*  bufA   = (float*)smem_raw;              // 16640 f
    float*  bufB   = bufA + BUF_F;                  // 16640 f
    float2* erec   = (float2*)(bufB + BUF_F);       // 2048 * {coef, pk}
    float*  deg    = (float*)(erec + NE);           // 256
    float*  score  = deg + NN;                      // 256
    float*  sctmp  = score + NN;                    // 256
    int*    rnkcnt = (int*)(sctmp + NN);            // 256
    float*  feats  = (float*)(rnkcnt + NN);         // 128
    float*  pn     = feats + 2 * HD;                // 64
    float*  mlp1   = pn + HD;                       // 64
    float*  mlp2   = mlp1 + HD;                     // 32
    unsigned short* epack0 = (unsigned short*)(mlp2 + 32);  // 2048 (orig packed edges)
    short*  nodemap = (short*)(epack0 + NE);                // 256 (orig id -> current id, -1 dropped)
    // readout partials alias the edge records (dead between P5 and next-layer P1)
    float*  redmax = (float*)erec;                  // 16*64
    float*  redsum = redmax + 16 * HD;              // 16*64

    const int tid = threadIdx.x;
    const int b   = blockIdx.x;

    // ---- load inputs into LDS ----
    {
        const int* eb = gedge + (size_t)b * 2 * NE;
        for (int e = tid; e < NE; e += NT) {
            int s0 = eb[e];
            int d0 = eb[NE + e];
            epack0[e] = (unsigned short)((s0 & 0xFF) | ((d0 & 0xFF) << 8));
        }
        const float* xb = gx + (size_t)b * NN * EMB;
        for (int i = tid; i < NN * EMB; i += NT) {
            bufA[(i / EMB) * STRIDE + (i % EMB)] = xb[i];
        }
        if (tid < NN) nodemap[tid] = (short)tid;
        if (tid < 2 * HD) feats[tid] = 0.f;
    }
    __syncthreads();

    float* cur = bufA;   // current node features (n x fin)
    float* nxt = bufB;   // scratch: h, then pooled output
    int n = NN;
    int fin = EMB;
    const float* Ws[3] = {W1, W2, W3};
    const float* bs[3] = {b1, b2, b3};
    const float* ps[3] = {p1, p2, p3};
    const int    ks[3] = {K1, K2, K3};

    for (int L = 0; L < 3; L++) {
        const float* W  = Ws[L];
        const float* bb = bs[L];
        const float* pp = ps[L];
        const int k = ks[L];

        // A: deg=1 for ALL 256 rows (TRASH row must give rsqrt(1)); pn = p/||p|| (wave 0)
        if (tid < NN) deg[tid] = 1.0f;
        if (tid < HD) {
            float pv = pp[tid];
            float s2 = pv * pv;
            #pragma unroll
            for (int off = 32; off >= 1; off >>= 1) s2 += __shfl_xor(s2, off, 64);
            pn[tid] = pv * rsqrtf(s2);
        }
        __syncthreads();

        // B: remap orig edges through cumulative map; validity in .x; accumulate degree
        for (int e = tid; e < NE; e += NT) {
            int pk0 = epack0[e];
            int s = nodemap[pk0 & 0xFF];
            int d = nodemap[pk0 >> 8];
            bool v = (s >= 0) && (d >= 0);
            float2 r;
            r.x = v ? 1.f : 0.f;
            r.y = __uint_as_float(v ? (unsigned)(s | (d << 16)) : (unsigned)(TRASH << 16));
            erec[e] = r;
            if (v) atomicAdd(&deg[d], 1.0f);
        }
        __syncthreads();

        // C: finalize coef = v * rsqrt(deg_s) * rsqrt(deg_d); dense h = x @ W (4 thr/node x 16 out)
        for (int e = tid; e < NE; e += NT) {
            float2 r = erec[e];
            unsigned pk = __float_as_uint(r.y);
            r.x = r.x * rsqrtf(deg[pk & 0xFFFF]) * rsqrtf(deg[pk >> 16]);
            erec[e] = r;
        }
        {
            int node = tid & (NN - 1);
            int q4 = __builtin_amdgcn_readfirstlane(tid >> 8); // wave-uniform 0..3 -> scalar W loads
            if (node < n) {
                float acc[16];
                #pragma unroll
                for (int j = 0; j < 16; j++) acc[j] = 0.f;
                const float* Wp = W + q4 * 16;
                const float* xrow = cur + node * STRIDE;
                for (int kk = 0; kk < fin; kk++) {
                    float xv = xrow[kk];
                    #pragma unroll
                    for (int j = 0; j < 16; j++) acc[j] = fmaf(xv, Wp[kk * HD + j], acc[j]);
                }
                float* hrow = nxt + node * STRIDE + q4 * 16;
                #pragma unroll
                for (int j = 0; j < 16; j++) hrow[j] = acc[j];
            }
        }
        __syncthreads();

        // D: zero agg region (cur is dead as x now) + score/rank scratch
        for (int i = tid; i < n * HD; i += NT) cur[(i >> 6) * STRIDE + (i & 63)] = 0.f;
        if (tid < NN) { sctmp[tid] = 0.f; rnkcnt[tid] = 0; }
        __syncthreads();

        // E: scatter-aggregate, branch-free. wave-per-edge, lane=feature.
        // ds_read_b64 rec -> h row read -> no-return ds_add (no dependency) => pipelines.
        {
            int lane = tid & 63;
            int wv = tid >> 6;  // 0..15
            #pragma unroll 4
            for (int e = wv; e < NE; e += 16) {
                float2 r = erec[e];
                unsigned pk = __float_as_uint(r.y);
                float hv = nxt[(pk & 0xFFFF) * STRIDE + lane];
                atomicAdd(&cur[(pk >> 16) * STRIDE + lane], hv * r.x);
            }
        }
        __syncthreads();

        // F: out = relu(agg + h/deg + b); score dot partials
        {
            int node = tid & (NN - 1);
            int q4 = __builtin_amdgcn_readfirstlane(tid >> 8);
            if (node < n) {
                float inv = 1.0f / deg[node];
                int jo = q4 * 16;
                float sc = 0.f;
                float* crow = cur + node * STRIDE + jo;
                const float* hrow = nxt + node * STRIDE + jo;
                #pragma unroll
                for (int j = 0; j < 16; j++) {
                    float o = crow[j] + hrow[j] * inv + bb[jo + j];
                    o = fmaxf(o, 0.f);
                    crow[j] = o;
                    sc = fmaf(o, pn[jo + j], sc);
                }
                atomicAdd(&sctmp[node], sc);
            }
        }
        __syncthreads();

        // G: score = tanh(.)
        if (tid < NN) score[tid] = tanhf(sctmp[tid]);
        __syncthreads();

        // H: rank by counting, 4 threads/node each scanning a 64-wide j slice
        {
            int node = tid & (NN - 1);
            int q4 = tid >> 8;
            float si = score[node];
            int j0 = q4 * 64;
            int j1 = j0 + 64 < n ? j0 + 64 : n;
            int cnt = 0;
            for (int j = j0; j < j1; j++) {
                float sj = score[j];          // broadcast read
                cnt += (sj > si) || (sj == si && j < node);
            }
            if (node < n && cnt) atomicAdd(&rnkcnt[node], cnt);
        }
        __syncthreads();

        // I: pool selected rows (x * tanh-score) into nxt; compose cumulative node map
        {
            int node = tid & (NN - 1);
            int q4 = tid >> 8;
            if (node < n) {
                int r = rnkcnt[node];
                if (r < k) {
                    float v = score[node];
                    const float* srow = cur + node * STRIDE + q4 * 16;
                    float* drow = nxt + r * STRIDE + q4 * 16;
                    #pragma unroll
                    for (int j = 0; j < 16; j++) drow[j] = srow[j] * v;
                }
            }
        }
        if (tid < NN) {
            int m = nodemap[tid];
            if (m >= 0) {
                int r = rnkcnt[m];
                nodemap[tid] = (short)((r < k) ? r : -1);
            }
        }
        __syncthreads();

        // J: readout partials (16 row-groups); redmax/redsum alias erec (dead until next B)
        {
            int f = tid & 63;
            int q = tid >> 6;
            float mx = -3.0e38f, sm = 0.f;
            for (int i = q; i < k; i += 16) {
                float v = nxt[i * STRIDE + f];
                mx = fmaxf(mx, v);
                sm += v;
            }
            redmax[q * 64 + f] = mx;
            redsum[q * 64 + f] = sm;
        }
        __syncthreads();
        if (tid < HD) {
            float mx = redmax[tid], sm = redsum[tid];
            #pragma unroll
            for (int q = 1; q < 16; q++) {
                mx = fmaxf(mx, redmax[q * 64 + tid]);
                sm += redsum[q * 64 + tid];
            }
            feats[tid] += mx;
            feats[HD + tid] += sm / (float)k;
        }
        __syncthreads();

        // ping-pong
        float* t = cur; cur = nxt; nxt = t;
        n = k;
        fin = HD;
    }

    // ---- final MLP: 128 -> 64 -> 32 -> 1, sigmoid ----
    if (tid < 64) {
        float a = lb1[tid];
        for (int i = 0; i < 2 * HD; i++) a = fmaf(feats[i], lW1[i * 64 + tid], a);
        mlp1[tid] = fmaxf(a, 0.f);
    }
    __syncthreads();
    if (tid < 32) {
        float a = lb2[tid];
        for (int i = 0; i < 64; i++) a = fmaf(mlp1[i], lW2[i * 32 + tid], a);
        mlp2[tid] = fmaxf(a, 0.f);
    }
    __syncthreads();
    if (tid == 0) {
        float a = lb3[0];
        for (int i = 0; i < 32; i++) a = fmaf(mlp2[i], lW3[i], a);
        gout[b] = 1.0f / (1.0f + expf(-a));
    }
}

extern "C" void kernel_launch(void* const* d_in, const int* in_sizes, int n_in,
                              void* d_out, int out_size, void* d_ws, size_t ws_size,
                              hipStream_t stream) {
    const float* gx    = (const float*)d_in[0];
    const int*   gedge = (const int*)d_in[1];
    const float* W1 = (const float*)d_in[2];
    const float* b1 = (const float*)d_in[3];
    const float* p1 = (const float*)d_in[4];
    const float* W2 = (const float*)d_in[5];
    const float* b2 = (const float*)d_in[6];
    const float* p2 = (const float*)d_in[7];
    const float* W3 = (const float*)d_in[8];
    const float* b3 = (const float*)d_in[9];
    const float* p3 = (const float*)d_in[10];
    const float* lW1 = (const float*)d_in[11];
    const float* lb1 = (const float*)d_in[12];
    const float* lW2 = (const float*)d_in[13];
    const float* lb2 = (const float*)d_in[14];
    const float* lW3 = (const float*)d_in[15];
    const float* lb3 = (const float*)d_in[16];
    float* gout = (float*)d_out;

    (void)hipFuncSetAttribute((const void*)gnn_pool_kernel,
                              hipFuncAttributeMaxDynamicSharedMemorySize, SMEM_BYTES);

    gnn_pool_kernel<<<NGRAPH, NT, SMEM_BYTES, stream>>>(
        gx, gedge, W1, b1, p1, W2, b2, p2, W3, b3, p3,
        lW1, lb1, lW2, lb2, lW3, lb3, gout);
}

// Round 3
// 489.431 us; speedup vs baseline: 5.2543x; 5.2543x over previous
//
#include <hip/hip_runtime.h>
#include <math.h>

#define NGRAPH 1024
#define NN     256
#define NE     2048
#define EMB    39
#define HD     64
#define STRIDE 65     // all LDS row ops are b32 at stride 65 -> <=2-way bank alias (free, m136)
#define NT     512    // 8 waves; 2 blocks/CU (LDS 78.5KB) -> 16 waves/CU
#define K1 205
#define K2 164
#define K3 132

// LDS map (bytes):
//  feat   256*65*4 = 66560   one buffer: x -> h (in place) -> pooled
//  red    1024 f   = 4096    aliases epk (ushort[2048]): epk dead after CSR fill, red used at readout
//  partial 512 f   = 2048    aliases col (uchar[2048]) + ipart (int[512]); barrier-separated
//  cnt    260 i    = 1040    degree counts -> exclusive offsets (in-place scan)
//  cur    256 i    = 1024    CSR fill cursors -> later rank array
//  dinv   256 f    = 1024
//  score  256 f    = 1024
//  feats  128 f    = 512
//  pn      64 f    = 256
//  mlp1    64 f    = 256
//  mlp2    32 f    = 128
//  nodemap 256 s   = 512
//  total = 78480  -> 2 blocks/CU
#define SMEM_BYTES 78480

struct Lds {
    float* feat; float* red; unsigned short* epk;
    float* partial; unsigned char* col; int* ipart;
    int* cnt; int* cur; float* dinv; float* score;
    float* feats; float* pn; float* mlp1; float* mlp2; short* nodemap;
};

template<int FIN>
__device__ __forceinline__ void layer_body(
    const Lds& S, const int* __restrict__ eb,
    const float* __restrict__ W, const float* __restrict__ bvec,
    const float* __restrict__ pvec, int n, int kkeep, int tid)
{
    const int node = tid & 255;
    const int q    = tid >> 8;       // 0/1: feature half
    const int jo   = q * 32;
    const int lane = tid & 63;
    const bool active = node < n;

    // B0: zero counts; wave0 computes pn = p/||p||
    if (tid < 258) S.cnt[tid] = 0;
    if (tid < 64) {
        float pv = pvec[tid];
        float s2 = pv * pv;
        #pragma unroll
        for (int off = 32; off >= 1; off >>= 1) s2 += __shfl_xor(s2, off, 64);
        S.pn[tid] = pv * rsqrtf(s2);
    }
    __syncthreads();

    // B1: pass1 — remap orig edges via cumulative nodemap; int-atomic degree count
    for (int e = tid; e < NE; e += NT) {
        int s0 = eb[e];
        int d0 = eb[NE + e];
        int s = S.nodemap[s0];
        int d = S.nodemap[d0];
        unsigned short pk = 0xFFFFu;
        if ((s | d) >= 0) {                 // both >= 0
            pk = (unsigned short)(s | (d << 8));
            atomicAdd(&S.cnt[d], 1);        // native ds_add_u32
        }
        S.epk[e] = pk;
    }
    __syncthreads();

    // B2: exclusive scan of cnt[0..255] -> offsets, cnt[256] = total (single wave)
    if (tid < 64) {
        int base = tid * 4;
        int c0 = S.cnt[base], c1 = S.cnt[base + 1], c2 = S.cnt[base + 2], c3 = S.cnt[base + 3];
        int s4 = c0 + c1 + c2 + c3;
        int x = s4;
        #pragma unroll
        for (int off = 1; off < 64; off <<= 1) {
            int t = __shfl_up(x, off, 64);
            if (tid >= off) x += t;
        }
        int e0 = x - s4;
        S.cnt[base]     = e0;
        S.cnt[base + 1] = e0 + c0;
        S.cnt[base + 2] = e0 + c0 + c1;
        S.cnt[base + 3] = e0 + c0 + c1 + c2;
        if (tid == 63) S.cnt[256] = x;
    }
    __syncthreads();

    // B3: dinv = rsqrt(1+indeg); cursors = offsets
    if (tid < 256) {
        int o0 = S.cnt[tid], o1 = S.cnt[tid + 1];
        S.cur[tid]  = o0;
        S.dinv[tid] = rsqrtf((float)(1 + o1 - o0));
    }
    __syncthreads();

    // B4: CSR fill (int-atomic cursors) + h = x@W into registers (x read from LDS)
    for (int e = tid; e < NE; e += NT) {
        unsigned pk = S.epk[e];
        if (pk != 0xFFFFu) {
            int d = pk >> 8;
            int pos = atomicAdd(&S.cur[d], 1);   // ds_add_rtn_u32
            S.col[pos] = (unsigned char)(pk & 0xFFu);
        }
    }
    float h[32];
    if (active) {
        #pragma unroll
        for (int j = 0; j < 32; j++) h[j] = 0.f;
        const float* Wp   = W + jo;              // wave-uniform half -> scalar loads
        const float* xrow = S.feat + node * STRIDE;
        for (int k = 0; k < FIN; k++) {
            float xv = xrow[k];
            #pragma unroll
            for (int j = 0; j < 32; j++) h[j] = fmaf(xv, Wp[k * HD + j], h[j]);
        }
    }
    __syncthreads();    // all x reads done before any h write (in-place x->h)

    // B4b: write h rows
    if (active) {
        float* hrow = S.feat + node * STRIDE + jo;
        #pragma unroll
        for (int j = 0; j < 32; j++) hrow[j] = h[j];
    }
    __syncthreads();

    // B5: gather agg = dinv_d * sum(dinv_s * h_s); out = relu(agg + h/deg + b); score dot
    float out[32];
    float sc = 0.f;
    if (active) {
        int o0 = S.cnt[node], o1 = S.cnt[node + 1];
        float s1[32];
        #pragma unroll
        for (int j = 0; j < 32; j++) s1[j] = 0.f;
        for (int e = o0; e < o1; e++) {
            int s = S.col[e];
            float dv = S.dinv[s];
            const float* hsrc = S.feat + s * STRIDE + jo;
            #pragma unroll
            for (int j = 0; j < 32; j++) s1[j] = fmaf(dv, hsrc[j], s1[j]);
        }
        float dvd = S.dinv[node];
        float invdeg = dvd * dvd;               // 1/deg
        #pragma unroll
        for (int j = 0; j < 32; j++) {
            float o = fmaf(dvd, s1[j], fmaf(h[j], invdeg, bvec[jo + j]));
            o = fmaxf(o, 0.f);
            out[j] = o;
            sc = fmaf(o, S.pn[jo + j], sc);
        }
    }
    __syncthreads();    // col fully consumed -> partial may alias it

    // B6: score partials
    S.partial[tid] = sc;
    __syncthreads();

    // B7: score = tanh(dot)
    if (tid < 256) S.score[tid] = tanhf(S.partial[tid] + S.partial[tid + 256]);
    __syncthreads();

    // B8: rank by counting (2 threads/node, 128-wide slices; score[j] reads broadcast)
    {
        int j0 = q * 128;
        int j1 = j0 + 128 < n ? j0 + 128 : n;
        float si = S.score[node];
        int c = 0;
        for (int j = j0; j < j1; j++) {
            float sj = S.score[j];
            c += (sj > si) || (sj == si && j < node);
        }
        S.ipart[tid] = c;
    }
    __syncthreads();

    // B9: rank into cur (cursors dead)
    if (tid < 256) S.cur[tid] = S.ipart[tid] + S.ipart[tid + 256];
    __syncthreads();

    // B10: compose cumulative nodemap; pooled rows written from registers
    if (tid < 256) {
        int m = S.nodemap[tid];
        if (m >= 0) {
            int r = S.cur[m];
            S.nodemap[tid] = (short)((r < kkeep) ? r : -1);
        }
    }
    if (active) {
        int r = S.cur[node];
        if (r < kkeep) {
            float v = S.score[node];
            float* drow = S.feat + r * STRIDE + jo;
            #pragma unroll
            for (int j = 0; j < 32; j++) drow[j] = out[j] * v;
        }
    }
    __syncthreads();

    // B11: readout partials (wave-strided rows, lane=feature)
    {
        int w = tid >> 6;
        float mx = -3.4e38f, sm = 0.f;
        for (int r = w; r < kkeep; r += 8) {
            float v = S.feat[r * STRIDE + lane];
            mx = fmaxf(mx, v);
            sm += v;
        }
        S.red[w * 64 + lane]       = mx;
        S.red[512 + w * 64 + lane] = sm;
    }
    __syncthreads();

    // B12: combine into feats
    if (tid < 64) {
        float mx = S.red[tid], sm = S.red[512 + tid];
        #pragma unroll
        for (int w = 1; w < 8; w++) {
            mx = fmaxf(mx, S.red[w * 64 + tid]);
            sm += S.red[512 + w * 64 + tid];
        }
        S.feats[tid]      += mx;
        S.feats[64 + tid] += sm / (float)kkeep;
    }
    __syncthreads();
}

__global__ __launch_bounds__(NT, 4) void gnn_pool_kernel(
    const float* __restrict__ gx, const int* __restrict__ gedge,
    const float* __restrict__ W1, const float* __restrict__ b1, const float* __restrict__ p1,
    const float* __restrict__ W2, const float* __restrict__ b2, const float* __restrict__ p2,
    const float* __restrict__ W3, const float* __restrict__ b3, const float* __restrict__ p3,
    const float* __restrict__ lW1, const float* __restrict__ lb1,
    const float* __restrict__ lW2, const float* __restrict__ lb2,
    const float* __restrict__ lW3, const float* __restrict__ lb3,
    float* __restrict__ gout)
{
    extern __shared__ __align__(16) char smem_raw[];
    Lds S;
    S.feat    = (float*)smem_raw;                         // 16640 f
    S.red     = S.feat + NN * STRIDE;                     // 1024 f
    S.epk     = (unsigned short*)S.red;                   // alias
    S.partial = S.red + 1024;                             // 512 f
    S.col     = (unsigned char*)S.partial;                // alias
    S.ipart   = (int*)S.partial;                          // alias
    S.cnt     = (int*)(S.partial + 512);                  // 260 i
    S.cur     = S.cnt + 260;                              // 256 i
    S.dinv    = (float*)(S.cur + 256);                    // 256 f
    S.score   = S.dinv + 256;                             // 256 f
    S.feats   = S.score + 256;                            // 128 f
    S.pn      = S.feats + 128;                            // 64 f
    S.mlp1    = S.pn + 64;                                // 64 f
    S.mlp2    = S.mlp1 + 64;                              // 32 f
    S.nodemap = (short*)(S.mlp2 + 32);                    // 256 s

    const int tid = threadIdx.x;
    const int b   = blockIdx.x;
    const int* eb = gedge + (size_t)b * 2 * NE;

    // init: x -> feat rows, identity nodemap, zero feats
    {
        const float* xb = gx + (size_t)b * NN * EMB;
        for (int i = tid; i < NN * EMB; i += NT) {
            S.feat[(i / EMB) * STRIDE + (i % EMB)] = xb[i];
        }
        if (tid < NN) S.nodemap[tid] = (short)tid;
        if (tid < 2 * HD) S.feats[tid] = 0.f;
    }
    __syncthreads();

    layer_body<EMB>(S, eb, W1, b1, p1, NN, K1, tid);
    layer_body<HD >(S, eb, W2, b2, p2, K1, K2, tid);
    layer_body<HD >(S, eb, W3, b3, p3, K2, K3, tid);

    // final MLP: 128 -> 64 -> 32 -> 1, sigmoid
    if (tid < 64) {
        float a = lb1[tid];
        for (int i = 0; i < 2 * HD; i++) a = fmaf(S.feats[i], lW1[i * 64 + tid], a);
        S.mlp1[tid] = fmaxf(a, 0.f);
    }
    __syncthreads();
    if (tid < 32) {
        float a = lb2[tid];
        for (int i = 0; i < 64; i++) a = fmaf(S.mlp1[i], lW2[i * 32 + tid], a);
        S.mlp2[tid] = fmaxf(a, 0.f);
    }
    __syncthreads();
    if (tid == 0) {
        float a = lb3[0];
        for (int i = 0; i < 32; i++) a = fmaf(S.mlp2[i], lW3[i], a);
        gout[b] = 1.0f / (1.0f + expf(-a));
    }
}

extern "C" void kernel_launch(void* const* d_in, const int* in_sizes, int n_in,
                              void* d_out, int out_size, void* d_ws, size_t ws_size,
                              hipStream_t stream) {
    const float* gx    = (const float*)d_in[0];
    const int*   gedge = (const int*)d_in[1];
    const float* W1 = (const float*)d_in[2];
    const float* b1 = (const float*)d_in[3];
    const float* p1 = (const float*)d_in[4];
    const float* W2 = (const float*)d_in[5];
    const float* b2 = (const float*)d_in[6];
    const float* p2 = (const float*)d_in[7];
    const float* W3 = (const float*)d_in[8];
    const float* b3 = (const float*)d_in[9];
    const float* p3 = (const float*)d_in[10];
    const float* lW1 = (const float*)d_in[11];
    const float* lb1 = (const float*)d_in[12];
    const float* lW2 = (const float*)d_in[13];
    const float* lb2 = (const float*)d_in[14];
    const float* lW3 = (const float*)d_in[15];
    const float* lb3 = (const float*)d_in[16];
    float* gout = (float*)d_out;

    (void)hipFuncSetAttribute((const void*)gnn_pool_kernel,
                              hipFuncAttributeMaxDynamicSharedMemorySize, SMEM_BYTES);

    gnn_pool_kernel<<<NGRAPH, NT, SMEM_BYTES, stream>>>(
        gx, gedge, W1, b1, p1, W2, b2, p2, W3, b3, p3,
        lW1, lb1, lW2, lb2, lW3, lb3, gout);
}